// Round 8
// baseline (117.055 us; speedup 1.0000x reference)
//
#include <hip/hip_runtime.h>
#include <math.h>

#define TOTAL 2097152
#define N_SEG 4096
#define FEAT 64
#define WINDOW 3
#define ROWS_PER_BLOCK 1024
#define N_CHUNK (TOTAL / ROWS_PER_BLOCK)      // 2048
#define INIT_BLOCKS (N_SEG * FEAT / 4 / 256)  // 256 blocks of float4 fills

typedef float f32x4 __attribute__((ext_vector_type(4)));

__device__ __forceinline__ f32x4 vmax4(f32x4 a, f32x4 b) {
  f32x4 r;
  r.x = fmaxf(a.x, b.x);
  r.y = fmaxf(a.y, b.y);
  r.z = fmaxf(a.z, b.z);
  r.w = fmaxf(a.w, b.w);
  return r;
}

// ---------------------------------------------------------------------------
// Kernel A (fused): blocks 0..255 fill out[] with -inf; block 256 computes
// the exclusive prefix sum of sizes[4096] -> starts[4096] (in d_ws) using
// coalesced LDS staging + a 256-thread two-level scan.
// ---------------------------------------------------------------------------
__global__ __launch_bounds__(256) void dmax_setup_kernel(
    const int* __restrict__ sizes, int* __restrict__ starts,
    float* __restrict__ out) {
  const int b = blockIdx.x;
  const int t = threadIdx.x;

  if (b < INIT_BLOCKS) {
    const int i = b * 256 + t;
    f32x4 v = {-INFINITY, -INFINITY, -INFINITY, -INFINITY};
    reinterpret_cast<f32x4*>(out)[i] = v;
    return;
  }

  __shared__ int s_sz[N_SEG];
#pragma unroll
  for (int i = 0; i < N_SEG / 256; ++i) s_sz[t + i * 256] = sizes[t + i * 256];
  __syncthreads();

  const int lane = t & 63;
  const int wave = t >> 6;

  // thread t owns 16 consecutive sizes
  int s = 0;
#pragma unroll
  for (int i = 0; i < 16; ++i) s += s_sz[t * 16 + i];

  // wave-inclusive scan of per-thread sums
  int v = s;
#pragma unroll
  for (int d = 1; d < 64; d <<= 1) {
    int o = __shfl_up(v, d, 64);
    if (lane >= d) v += o;
  }

  __shared__ int wtot[4];
  if (lane == 63) wtot[wave] = v;
  __syncthreads();

  int wpre = 0;
  for (int w = 0; w < 4; ++w)
    if (w < wave) wpre += wtot[w];

  int run = wpre + v - s;  // exclusive prefix for this thread's 16
#pragma unroll
  for (int i = 0; i < 16; ++i) {
    starts[t * 16 + i] = run;
    run += s_sz[t * 16 + i];
  }
}

// ---------------------------------------------------------------------------
// Kernel B: balanced chunk kernel. One block per 1024 contiguous rows.
//   fchunk  = t & 15  -> which float4 of the 64-float feature row
//   rowslot = t >> 4  -> owns 8 CONSECUTIVE rows, superblock stride 128
// The 8 loads of a superblock are at imm offsets 0..1792B from one base.
// Walk segments overlapping this chunk; register-reduce each sub-range,
// then HW float atomicMax 64 values into out.
// (Round 8: plain loads — A/B test vs Round 7's nontemporal loads.)
// ---------------------------------------------------------------------------
__global__ __launch_bounds__(256) void dmax_chunk_kernel(
    const float* __restrict__ in, const int* __restrict__ sizes,
    const int* __restrict__ starts, float* __restrict__ out) {
  const int chunk_lo = blockIdx.x * ROWS_PER_BLOCK;
  const int chunk_hi = chunk_lo + ROWS_PER_BLOCK;  // TOTAL divisible

  const int t = threadIdx.x;
  const int fchunk = t & 15;
  const int rowslot = t >> 4;
  const int wave = t >> 6;

  // Binary search: largest seg with starts[seg] <= chunk_lo.
  int lo = 0, hi = N_SEG - 1;
  while (lo < hi) {
    int mid = (lo + hi + 1) >> 1;
    if (starts[mid] <= chunk_lo) lo = mid; else hi = mid - 1;
  }
  int seg = lo;

  __shared__ float red[4][FEAT];
  const f32x4* inv = reinterpret_cast<const f32x4*>(in);

  int row = chunk_lo;
  while (row < chunk_hi) {
    const int s_start = starts[seg];
    const int s_size = sizes[seg];
    const int s_vend = s_start + s_size - (WINDOW - 1);  // valid row end
    const int s_end = s_start + s_size;

    const int rlo = row;
    const int rhi = min(chunk_hi, s_vend);

    if (rhi > rlo) {
      f32x4 m0 = {-INFINITY, -INFINITY, -INFINITY, -INFINITY};
      f32x4 m1 = m0;

      int rb = rlo + rowslot * 8;
      const f32x4* p = inv + (size_t)rb * (FEAT / 4) + fchunk;

      // bulk: 8 rows per superblock, imm-offset loads
      for (; rb + 8 <= rhi; rb += 128, p += 128 * (FEAT / 4)) {
        f32x4 v0 = p[0 * 16];
        f32x4 v1 = p[1 * 16];
        f32x4 v2 = p[2 * 16];
        f32x4 v3 = p[3 * 16];
        f32x4 v4 = p[4 * 16];
        f32x4 v5 = p[5 * 16];
        f32x4 v6 = p[6 * 16];
        f32x4 v7 = p[7 * 16];
        m0 = vmax4(m0, vmax4(vmax4(v0, v1), vmax4(v2, v3)));
        m1 = vmax4(m1, vmax4(vmax4(v4, v5), vmax4(v6, v7)));
      }
      // tail: up to 7 remaining rows for this thread
      if (rb < rhi) {
        const int nrem = rhi - rb;  // 1..7
#pragma unroll
        for (int k = 0; k < 7; ++k) {
          if (k < nrem) {
            f32x4 v = p[k * 16];
            m0 = vmax4(m0, v);
          }
        }
      }
      f32x4 m = vmax4(m0, m1);

      // reduce rowslots within wave (t bits 4,5)
#pragma unroll
      for (int mask = 16; mask <= 32; mask <<= 1) {
        m.x = fmaxf(m.x, __shfl_xor(m.x, mask, 64));
        m.y = fmaxf(m.y, __shfl_xor(m.y, mask, 64));
        m.z = fmaxf(m.z, __shfl_xor(m.z, mask, 64));
        m.w = fmaxf(m.w, __shfl_xor(m.w, mask, 64));
      }
      __syncthreads();  // protect red[] from previous iteration's readers
      if ((t & 63) < 16) {
        red[wave][fchunk * 4 + 0] = m.x;
        red[wave][fchunk * 4 + 1] = m.y;
        red[wave][fchunk * 4 + 2] = m.z;
        red[wave][fchunk * 4 + 3] = m.w;
      }
      __syncthreads();
      if (t < FEAT) {
        float v = fmaxf(fmaxf(red[0][t], red[1][t]),
                        fmaxf(red[2][t], red[3][t]));
        // HW global_atomic_fmax_f32: exact, order-independent (no NaNs).
        unsafeAtomicMax(out + (size_t)seg * FEAT + t, v);
      }
    }

    row = min(chunk_hi, s_end);
    ++seg;
  }
}

extern "C" void kernel_launch(void* const* d_in, const int* in_sizes, int n_in,
                              void* d_out, int out_size, void* d_ws, size_t ws_size,
                              hipStream_t stream) {
  const float* input = (const float*)d_in[0];
  const int* sizes = (const int*)d_in[1];
  float* out = (float*)d_out;
  int* starts = (int*)d_ws;  // 16 KB scratch

  dmax_setup_kernel<<<INIT_BLOCKS + 1, 256, 0, stream>>>(sizes, starts, out);
  dmax_chunk_kernel<<<N_CHUNK, 256, 0, stream>>>(input, sizes, starts, out);
}

// Round 9
// 102.292 us; speedup vs baseline: 1.1443x; 1.1443x over previous
//
#include <hip/hip_runtime.h>
#include <math.h>

#define TOTAL 2097152
#define N_SEG 4096
#define FEAT 64
#define WINDOW 3
#define ROWS_PER_BLOCK 1024
#define N_CHUNK (TOTAL / ROWS_PER_BLOCK)      // 2048
#define INIT_BLOCKS (N_SEG * FEAT / 4 / 256)  // 256 blocks of float4 fills

typedef float f32x4 __attribute__((ext_vector_type(4)));

__device__ __forceinline__ f32x4 nt_load(const f32x4* p) {
  return __builtin_nontemporal_load(p);
}

__device__ __forceinline__ f32x4 vmax4(f32x4 a, f32x4 b) {
  f32x4 r;
  r.x = fmaxf(a.x, b.x);
  r.y = fmaxf(a.y, b.y);
  r.z = fmaxf(a.z, b.z);
  r.w = fmaxf(a.w, b.w);
  return r;
}

// ---------------------------------------------------------------------------
// Kernel A (fused): blocks 0..255 fill out[] with -inf; block 256 computes
// the exclusive prefix sum of sizes[4096] -> starts[4096] (in d_ws) using
// coalesced LDS staging + a 256-thread two-level scan.
// ---------------------------------------------------------------------------
__global__ __launch_bounds__(256) void dmax_setup_kernel(
    const int* __restrict__ sizes, int* __restrict__ starts,
    float* __restrict__ out) {
  const int b = blockIdx.x;
  const int t = threadIdx.x;

  if (b < INIT_BLOCKS) {
    const int i = b * 256 + t;
    f32x4 v = {-INFINITY, -INFINITY, -INFINITY, -INFINITY};
    reinterpret_cast<f32x4*>(out)[i] = v;
    return;
  }

  __shared__ int s_sz[N_SEG];
#pragma unroll
  for (int i = 0; i < N_SEG / 256; ++i) s_sz[t + i * 256] = sizes[t + i * 256];
  __syncthreads();

  const int lane = t & 63;
  const int wave = t >> 6;

  // thread t owns 16 consecutive sizes
  int s = 0;
#pragma unroll
  for (int i = 0; i < 16; ++i) s += s_sz[t * 16 + i];

  // wave-inclusive scan of per-thread sums
  int v = s;
#pragma unroll
  for (int d = 1; d < 64; d <<= 1) {
    int o = __shfl_up(v, d, 64);
    if (lane >= d) v += o;
  }

  __shared__ int wtot[4];
  if (lane == 63) wtot[wave] = v;
  __syncthreads();

  int wpre = 0;
  for (int w = 0; w < 4; ++w)
    if (w < wave) wpre += wtot[w];

  int run = wpre + v - s;  // exclusive prefix for this thread's 16
#pragma unroll
  for (int i = 0; i < 16; ++i) {
    starts[t * 16 + i] = run;
    run += s_sz[t * 16 + i];
  }
}

// ---------------------------------------------------------------------------
// Kernel B: balanced chunk kernel. One block per 1024 contiguous rows.
//   fchunk  = t & 15  -> which float4 of the 64-float feature row
//   rowslot = t >> 4  -> INTERLEAVED row ownership: row = rb + rowslot,
//                        stride 16. Each wave-instruction reads 1KB fully
//                        contiguous (4 rowslots x 4 consecutive rows x 256B).
// 8 nt-loads in flight per thread (128 rows per superblock iteration).
// Walk segments overlapping this chunk; register-reduce each sub-range,
// then HW float atomicMax 64 values into out.
// ---------------------------------------------------------------------------
__global__ __launch_bounds__(256) void dmax_chunk_kernel(
    const float* __restrict__ in, const int* __restrict__ sizes,
    const int* __restrict__ starts, float* __restrict__ out) {
  const int chunk_lo = blockIdx.x * ROWS_PER_BLOCK;
  const int chunk_hi = chunk_lo + ROWS_PER_BLOCK;  // TOTAL divisible

  const int t = threadIdx.x;
  const int fchunk = t & 15;
  const int rowslot = t >> 4;
  const int wave = t >> 6;

  // Binary search: largest seg with starts[seg] <= chunk_lo.
  int lo = 0, hi = N_SEG - 1;
  while (lo < hi) {
    int mid = (lo + hi + 1) >> 1;
    if (starts[mid] <= chunk_lo) lo = mid; else hi = mid - 1;
  }
  int seg = lo;

  __shared__ float red[4][FEAT];
  const f32x4* inv = reinterpret_cast<const f32x4*>(in);

  int row = chunk_lo;
  while (row < chunk_hi) {
    const int s_start = starts[seg];
    const int s_size = sizes[seg];
    const int s_vend = s_start + s_size - (WINDOW - 1);  // valid row end
    const int s_end = s_start + s_size;

    const int rlo = row;
    const int rhi = min(chunk_hi, s_vend);

    if (rhi > rlo) {
      f32x4 m0 = {-INFINITY, -INFINITY, -INFINITY, -INFINITY};
      f32x4 m1 = m0;

      int rb = rlo;  // thread handles rows rb + rowslot, stride 16
      const f32x4* p = inv + (size_t)(rb + rowslot) * (FEAT / 4) + fchunk;
      const int RSTRIDE = 16 * (FEAT / 4);  // 16 rows in f32x4 units (4KB)

      // bulk: 128 rows per iteration, 8 nt-loads in flight
      for (; rb + 128 <= rhi; rb += 128, p += 8 * RSTRIDE) {
        f32x4 v0 = nt_load(p + 0 * RSTRIDE);
        f32x4 v1 = nt_load(p + 1 * RSTRIDE);
        f32x4 v2 = nt_load(p + 2 * RSTRIDE);
        f32x4 v3 = nt_load(p + 3 * RSTRIDE);
        f32x4 v4 = nt_load(p + 4 * RSTRIDE);
        f32x4 v5 = nt_load(p + 5 * RSTRIDE);
        f32x4 v6 = nt_load(p + 6 * RSTRIDE);
        f32x4 v7 = nt_load(p + 7 * RSTRIDE);
        m0 = vmax4(m0, vmax4(vmax4(v0, v1), vmax4(v2, v3)));
        m1 = vmax4(m1, vmax4(vmax4(v4, v5), vmax4(v6, v7)));
      }
      // tail: remaining rows (< 128) at stride 16
      for (int r = rb + rowslot; r < rhi; r += 16) {
        f32x4 v = nt_load(inv + (size_t)r * (FEAT / 4) + fchunk);
        m0 = vmax4(m0, v);
      }
      f32x4 m = vmax4(m0, m1);

      // reduce rowslots within wave (t bits 4,5)
#pragma unroll
      for (int mask = 16; mask <= 32; mask <<= 1) {
        m.x = fmaxf(m.x, __shfl_xor(m.x, mask, 64));
        m.y = fmaxf(m.y, __shfl_xor(m.y, mask, 64));
        m.z = fmaxf(m.z, __shfl_xor(m.z, mask, 64));
        m.w = fmaxf(m.w, __shfl_xor(m.w, mask, 64));
      }
      __syncthreads();  // protect red[] from previous iteration's readers
      if ((t & 63) < 16) {
        red[wave][fchunk * 4 + 0] = m.x;
        red[wave][fchunk * 4 + 1] = m.y;
        red[wave][fchunk * 4 + 2] = m.z;
        red[wave][fchunk * 4 + 3] = m.w;
      }
      __syncthreads();
      if (t < FEAT) {
        float v = fmaxf(fmaxf(red[0][t], red[1][t]),
                        fmaxf(red[2][t], red[3][t]));
        // HW global_atomic_fmax_f32: exact, order-independent (no NaNs).
        unsafeAtomicMax(out + (size_t)seg * FEAT + t, v);
      }
    }

    row = min(chunk_hi, s_end);
    ++seg;
  }
}

extern "C" void kernel_launch(void* const* d_in, const int* in_sizes, int n_in,
                              void* d_out, int out_size, void* d_ws, size_t ws_size,
                              hipStream_t stream) {
  const float* input = (const float*)d_in[0];
  const int* sizes = (const int*)d_in[1];
  float* out = (float*)d_out;
  int* starts = (int*)d_ws;  // 16 KB scratch

  dmax_setup_kernel<<<INIT_BLOCKS + 1, 256, 0, stream>>>(sizes, starts, out);
  dmax_chunk_kernel<<<N_CHUNK, 256, 0, stream>>>(input, sizes, starts, out);
}